// Round 1
// baseline (72.747 us; speedup 1.0000x reference)
//
#include <hip/hip_runtime.h>
#include <cmath>

#define SITE 8
#define DIM 16
#define BATCH 8192
#define NPAT 256

// One block per 8-bit pattern. Builds the 7x2 per-site 16x16 matrices
// (embedding pre-contracted into body_w octants) then runs the recurrence.
__global__ __launch_bounds__(256) void pattern_kernel(
    const float* __restrict__ embedding,  // (8,2,16)
    const float* __restrict__ head_w,     // (32,32)
    const float* __restrict__ body_w,     // (7,32,32,32)
    float* __restrict__ pat)              // (256,32): [e(16), o(16)]
{
    __shared__ float M[7][2][16][16];   // [site-1][0:even-prod,1:odd-prod][k][j]
    __shared__ float se[16], so[16];
    const int p = blockIdx.x;
    const int tid = threadIdx.x;

    // ---- Phase 1: build this pattern's matrices (3584 entries / 256 thr) ----
    #pragma unroll
    for (int r = 0; r < 14; ++r) {
        int t = tid + 256 * r;        // 0..3583
        int s = t >> 9;               // site-1 in 0..6
        int rem = t & 511;
        int h = rem >> 8;             // 0: even-producing, 1: odd-producing
        int e = rem & 255;
        int k = e >> 4;
        int j = e & 15;
        int bit = (p >> (s + 1)) & 1;
        const float* g3 = body_w + s * 32768;
        const float* emb = embedding + (s + 1) * 32 + bit * 16;
        float acc = 0.f;
        if (bit == 0) {
            if (h == 0) {   // A0[k][j] = sum_i emb0[i]*g3[k][i][j]       (LLL)
                #pragma unroll
                for (int i = 0; i < 16; ++i) acc += emb[i] * g3[k*1024 + i*32 + j];
            } else {        // B0[k][j] = sum_i emb0[i]*g3[k+16][i][j+16] (HLH)
                #pragma unroll
                for (int i = 0; i < 16; ++i) acc += emb[i] * g3[(k+16)*1024 + i*32 + (j+16)];
            }
        } else {
            if (h == 0) {   // A1[k][j] = -sum_i emb1[i]*g3[k+16][i+16][j] (HHL, sign from SWSIGN)
                #pragma unroll
                for (int i = 0; i < 16; ++i) acc -= emb[i] * g3[(k+16)*1024 + (i+16)*32 + j];
            } else {        // B1[k][j] = sum_i emb1[i]*g3[k][i+16][j+16]  (LHH)
                #pragma unroll
                for (int i = 0; i < 16; ++i) acc += emb[i] * g3[k*1024 + (i+16)*32 + (j+16)];
            }
        }
        M[s][h][k][j] = acc;
    }

    // ---- Phase 1b: head state (site 0) ----
    if (tid < 32) {
        int h = tid >> 4;   // 0: e, 1: o
        int j = tid & 15;
        int bit0 = p & 1;
        float v = 0.f;
        if (bit0 == 0 && h == 0) {        // e[j] = tanh(sum_k emb00[k]*hw[k][j]), block LL
            const float* emb = embedding;             // site 0, row 0
            float a = 0.f;
            #pragma unroll
            for (int k = 0; k < 16; ++k) a += emb[k] * head_w[k*32 + j];
            v = tanhf(a);
        } else if (bit0 == 1 && h == 1) { // o[j] = tanh(sum_k emb01[k]*hw[k+16][j+16]), block HH
            const float* emb = embedding + 16;        // site 0, row 1
            float a = 0.f;
            #pragma unroll
            for (int k = 0; k < 16; ++k) a += emb[k] * head_w[(k+16)*32 + (j+16)];
            v = tanhf(a);
        }
        if (h == 0) se[j] = v; else so[j] = v;
    }
    __syncthreads();

    // ---- Phase 2: 7-step recurrence (threads 0..31 active) ----
    for (int s = 1; s < SITE; ++s) {
        float nv = 0.f;
        if (tid < 32) {
            int h = tid >> 4;
            int j = tid & 15;
            int bit = (p >> s) & 1;
            // bit0: e'<-e, o'<-o ; bit1: e'<-o, o'<-e  (input swap)
            const float* src = (h == 0) ? (bit ? so : se) : (bit ? se : so);
            const float* m = &M[s-1][h][0][0];
            float a = 0.f;
            #pragma unroll
            for (int k = 0; k < 16; ++k) a += src[k] * m[k*16 + j];
            nv = tanhf(a);
        }
        __syncthreads();
        if (tid < 32) {
            int h = tid >> 4; int j = tid & 15;
            if (h == 0) se[j] = nv; else so[j] = nv;
        }
        __syncthreads();
    }

    if (tid < 32) {
        int h = tid >> 4; int j = tid & 15;
        pat[p * 32 + tid] = (h == 0) ? se[j] : so[j];
    }
}

// Scatter: each 64-thread group handles one sample, writes [e, 0, 0, o].
__global__ __launch_bounds__(256) void scatter_kernel(
    const int* __restrict__ data,   // (8192,8)
    const float* __restrict__ pat,  // (256,32)
    float* __restrict__ out)        // (8192,2,32)
{
    int gid = blockIdx.x * 256 + threadIdx.x;
    int b = gid >> 6;
    int t = gid & 63;
    if (b >= BATCH) return;
    const int* db = data + b * 8;
    int id = 0;
    #pragma unroll
    for (int i = 0; i < 8; ++i) id |= (db[i] & 1) << i;
    float v = 0.f;
    if (t < 16) v = pat[id * 32 + t];
    else if (t >= 48) v = pat[id * 32 + 16 + (t - 48)];
    out[b * 64 + t] = v;
}

extern "C" void kernel_launch(void* const* d_in, const int* in_sizes, int n_in,
                              void* d_out, int out_size, void* d_ws, size_t ws_size,
                              hipStream_t stream) {
    const int*   data      = (const int*)d_in[0];
    const float* embedding = (const float*)d_in[1];
    const float* head_w    = (const float*)d_in[2];
    const float* body_w    = (const float*)d_in[3];
    float* out = (float*)d_out;
    float* pat = (float*)d_ws;   // 256*32 floats = 32 KB

    pattern_kernel<<<NPAT, 256, 0, stream>>>(embedding, head_w, body_w, pat);
    scatter_kernel<<<(BATCH * 64) / 256, 256, 0, stream>>>(data, pat, out);
}